// Round 3
// baseline (2919.891 us; speedup 1.0000x reference)
//
#include <hip/hip_runtime.h>
#include <hip/hip_fp16.h>

#define LQ    42875      // 35^3 tokens
#define NTOK  343
#define X1SZ  2058000    // LQ*48

// ws float offsets. Base usage ~150 KB; O-path adds 33 MB (gated on ws_size).
#define OFF_MEAN 0       // 48 channel sums + 1 gate scalar
#define OFF_W1T  64      // w1^T: [s][384][48], 2*18432 floats
#define OFF_O    36928   // O[s][w][i][96]: 8,232,000 floats (only if ws_size>=34MB)
#define O_BYTES_NEEDED 34000000ull

__device__ __forceinline__ int src_index(int w, int i, int& par) {
  int gi = w / 25, gj = (w / 5) % 5, gk = w % 5;
  int ph = i / 49, pw = (i / 7) % 7, pt = i % 7;
  int hs = gi * 7 + ph + 3; if (hs >= 35) hs -= 35;
  int wd = gj * 7 + pw + 3; if (wd >= 35) wd -= 35;
  int td = gk * 7 + pt + 3; if (td >= 35) td -= 35;
  par = ((hs / 7) + (wd / 7) + (td / 7)) & 1;
  return (hs * 35 + wd) * 35 + td;
}

// K0: zero gate meanbuf; optionally prefill d_out = x0 + proj_bias (atomic path)
__global__ __launch_bounds__(256) void k_init(
    const float* __restrict__ xa, const float* __restrict__ xb,
    const float* __restrict__ pba, const float* __restrict__ pbb,
    float* __restrict__ out, float* __restrict__ ws, int prefill) {
  if (blockIdx.x == 0 && threadIdx.x < 49) ws[threadIdx.x] = 0.f;
  if (!prefill) return;
  int idx4 = blockIdx.x * 256 + threadIdx.x;
  if (idx4 >= 2 * (X1SZ / 4)) return;
  int s = (idx4 >= (X1SZ / 4)) ? 1 : 0;
  int j4 = idx4 - s * (X1SZ / 4);
  int c0 = (j4 * 4) % 48;
  float4 xv = ((const float4*)(s ? xb : xa))[j4];
  const float* pb = (s ? pbb : pba) + c0;
  float4 o;
  o.x = xv.x + pb[0]; o.y = xv.y + pb[1]; o.z = xv.z + pb[2]; o.w = xv.w + pb[3];
  ((float4*)out)[idx4] = o;
}

// K0b: transpose fc1 weights (48,384)->(384,48) for contiguous k_mlp rows
__global__ __launch_bounds__(256) void k_tr(
    const float* __restrict__ w1a, const float* __restrict__ w1b,
    float* __restrict__ ws) {
  int idx = blockIdx.x * 256 + threadIdx.x;
  if (idx >= 2 * 18432) return;
  int s = (idx >= 18432) ? 1 : 0;
  int e = idx - s * 18432;
  int j = e / 48, k = e - j * 48;
  ws[OFF_W1T + s * 18432 + j * 48 + k] = (s ? w1b : w1a)[k * 384 + j];
}

// per-token fused LN1 + shuffle-gather + QKV for one head; verified round 2
__device__ __forceinline__ int qkv_one(
    int w, int i, int s,
    const float* __restrict__ xa, const float* __restrict__ xb,
    const float* __restrict__ ga, const float* __restrict__ ba,
    const float* __restrict__ gb, const float* __restrict__ bb,
    const float* __restrict__ qw, const float* __restrict__ qb, int h,
    float* __restrict__ qout, float* kk, float* vv) {
  int par; int src = src_index(w, i, par);
  const float* xo = (s ? xb : xa) + src * 48;
  const float* xt = (s ? xa : xb) + src * 48;
  const float* go = s ? gb : ga; const float* bo = s ? bb : ba;
  const float* gt = s ? ga : gb; const float* bt = s ? ba : bb;
  float own[48], up[48];
  {
    float v[48]; float sm = 0.f, sq = 0.f;
#pragma unroll
    for (int q4 = 0; q4 < 12; q4++) {
      float4 tv = ((const float4*)xo)[q4];
      v[4 * q4] = tv.x; v[4 * q4 + 1] = tv.y; v[4 * q4 + 2] = tv.z; v[4 * q4 + 3] = tv.w;
      sm += tv.x + tv.y + tv.z + tv.w;
      sq += tv.x * tv.x + tv.y * tv.y + tv.z * tv.z + tv.w * tv.w;
    }
    float m = sm * (1.f / 48.f);
    float r = rsqrtf(sq * (1.f / 48.f) - m * m + 1e-5f);
#pragma unroll
    for (int k = 0; k < 48; k++) own[k] = (v[k] - m) * r * go[k] + bo[k];
  }
  {
    float v[48]; float sm = 0.f, sq = 0.f;
#pragma unroll
    for (int q4 = 0; q4 < 12; q4++) {
      float4 tv = ((const float4*)xt)[q4];
      v[4 * q4] = tv.x; v[4 * q4 + 1] = tv.y; v[4 * q4 + 2] = tv.z; v[4 * q4 + 3] = tv.w;
      sm += tv.x + tv.y + tv.z + tv.w;
      sq += tv.x * tv.x + tv.y * tv.y + tv.z * tv.z + tv.w * tv.w;
    }
    float m = sm * (1.f / 48.f);
    float r = rsqrtf(sq * (1.f / 48.f) - m * m + 1e-5f);
#pragma unroll
    for (int k = 0; k < 48; k++)
      up[k] = par ? own[k] : ((v[k] - m) * r * gt[k] + bt[k]);
  }
  const float* Wt = qw + 16 * h;
  const float* Bq = qb + 16 * h;
  float kr[16], vr[16];
#pragma unroll
  for (int d = 0; d < 16; d++) { qout[d] = 0.f; kr[d] = 0.f; vr[d] = 0.f; }
#pragma unroll
  for (int kx = 0; kx < 96; kx++) {
    float xv = (kx < 48) ? own[kx] : up[kx - 48];
    const float* row = Wt + kx * 288;
#pragma unroll
    for (int d = 0; d < 16; d++) {
      qout[d] = fmaf(xv, row[d], qout[d]);
      kr[d] = fmaf(xv, row[96 + d], kr[d]);
      vr[d] = fmaf(xv, row[192 + d], vr[d]);
    }
  }
#pragma unroll
  for (int d = 0; d < 16; d++) {
    qout[d] = (qout[d] + Bq[d]) * 0.25f;
    kr[d] += Bq[96 + d];
    vr[d] += Bq[192 + d];
  }
  float* kd = kk + i * 16; float* vd = vv + i * 16;
#pragma unroll
  for (int r4 = 0; r4 < 4; r4++) {
    float4 kvv = {kr[4 * r4], kr[4 * r4 + 1], kr[4 * r4 + 2], kr[4 * r4 + 3]};
    float4 vvv = {vr[4 * r4], vr[4 * r4 + 1], vr[4 * r4 + 2], vr[4 * r4 + 3]};
    ((float4*)kd)[r4] = kvv;
    ((float4*)vd)[r4] = vvv;
  }
  return src;
}

// K1: fused attention, block=(w,s,h) XCD-swizzled, 192 thr, 2 tokens/thread.
// Bias (mask+rpb) staged per 16-col tile in LDS fp16 with coalesced reads.
__global__ __launch_bounds__(192) void k_attn(
    const float* __restrict__ xa, const float* __restrict__ xb,
    const float* __restrict__ ga, const float* __restrict__ ba,
    const float* __restrict__ gb, const float* __restrict__ bb,
    const float* __restrict__ qwa, const float* __restrict__ qba,
    const float* __restrict__ qwb, const float* __restrict__ qbb,
    const float* __restrict__ pwa, const float* __restrict__ pwb,
    const float* __restrict__ rpa, const float* __restrict__ rpbp,
    const float* __restrict__ mask,
    float* __restrict__ out, float* __restrict__ obuf, int use_o) {
  int bid = blockIdx.x;
  int xcd = bid & 7, q8 = bid >> 3;
  int u = q8 / 12, inst = q8 - u * 12;
  int w = u * 8 + xcd;
  if (w >= 125) return;
  int s = inst & 1, h = inst >> 1;

  __shared__ float kk[NTOK * 16];     // 21952 B
  __shared__ float vv[NTOK * 16];     // 21952 B
  __shared__ float rpbl[2197];        //  8788 B
  __shared__ __half mt[NTOK * 17];    // 11662 B (pad 17: conflict-free)

  const float* rp = s ? rpbp : rpa;
  for (int idx = threadIdx.x; idx < 2197; idx += 192) rpbl[idx] = rp[idx * 6 + h];

  int t = threadIdx.x;
  bool act0 = (t < 172);
  bool act1 = (t < 171);
  int i1 = t + 172;              // second token (rows 172..342)
  int i1r = act1 ? i1 : 0;       // safe LDS row for inactive lane

  const float* qw = s ? qwb : qwa;
  const float* qb = s ? qbb : qba;
  float q0[16], q1[16];
#pragma unroll
  for (int d = 0; d < 16; d++) { q0[d] = 0.f; q1[d] = 0.f; }
  int src0 = 0, src1 = 0;
  if (act0) src0 = qkv_one(w, t, s, xa, xb, ga, ba, gb, bb, qw, qb, h, q0, kk, vv);
  if (act1) src1 = qkv_one(w, i1, s, xa, xb, ga, ba, gb, bb, qw, qb, h, q1, kk, vv);
  __syncthreads();

  const float* mbase = mask + (w * NTOK) * NTOK;
  float4 a00 = {0,0,0,0}, a01 = {0,0,0,0}, a02 = {0,0,0,0}, a03 = {0,0,0,0};
  float4 a10 = {0,0,0,0}, a11 = {0,0,0,0}, a12 = {0,0,0,0}, a13 = {0,0,0,0};
  float l0 = 0.f, l1 = 0.f;

  for (int jt = 0; jt < 22; jt++) {
    int j0 = jt * 16;
    int jmax = NTOK - j0; if (jmax > 16) jmax = 16;
    // stage bias tile: mt[row][col] = mask[w][row][j0+col] + rpb[RPI[row][j0+col]]
    for (int e = t; e < NTOK * 16; e += 192) {
      int row = e >> 4, col = e & 15;
      int j = j0 + col;
      if (j < NTOK) {
        int bj = (j / 49) * 169 + ((j / 7) % 7) * 13 + (j % 7);
        int bi = (row / 49) * 169 + ((row / 7) % 7) * 13 + (row % 7) + 1098;
        mt[row * 17 + col] = __float2half(mbase[row * NTOK + j] + rpbl[bi - bj]);
      }
    }
    __syncthreads();
    if (act0) {
      for (int jj = 0; jj < jmax; jj++) {
        int j = j0 + jj;
        const float4* kj = (const float4*)(kk + 16 * j);
        float4 k0 = kj[0], k1 = kj[1], k2 = kj[2], k3 = kj[3];
        float sv0 = q0[0] * k0.x, sv1 = q1[0] * k0.x;
        sv0 = fmaf(q0[1], k0.y, sv0); sv1 = fmaf(q1[1], k0.y, sv1);
        sv0 = fmaf(q0[2], k0.z, sv0); sv1 = fmaf(q1[2], k0.z, sv1);
        sv0 = fmaf(q0[3], k0.w, sv0); sv1 = fmaf(q1[3], k0.w, sv1);
        sv0 = fmaf(q0[4], k1.x, sv0); sv1 = fmaf(q1[4], k1.x, sv1);
        sv0 = fmaf(q0[5], k1.y, sv0); sv1 = fmaf(q1[5], k1.y, sv1);
        sv0 = fmaf(q0[6], k1.z, sv0); sv1 = fmaf(q1[6], k1.z, sv1);
        sv0 = fmaf(q0[7], k1.w, sv0); sv1 = fmaf(q1[7], k1.w, sv1);
        sv0 = fmaf(q0[8], k2.x, sv0); sv1 = fmaf(q1[8], k2.x, sv1);
        sv0 = fmaf(q0[9], k2.y, sv0); sv1 = fmaf(q1[9], k2.y, sv1);
        sv0 = fmaf(q0[10], k2.z, sv0); sv1 = fmaf(q1[10], k2.z, sv1);
        sv0 = fmaf(q0[11], k2.w, sv0); sv1 = fmaf(q1[11], k2.w, sv1);
        sv0 = fmaf(q0[12], k3.x, sv0); sv1 = fmaf(q1[12], k3.x, sv1);
        sv0 = fmaf(q0[13], k3.y, sv0); sv1 = fmaf(q1[13], k3.y, sv1);
        sv0 = fmaf(q0[14], k3.z, sv0); sv1 = fmaf(q1[14], k3.z, sv1);
        sv0 = fmaf(q0[15], k3.w, sv0); sv1 = fmaf(q1[15], k3.w, sv1);
        float b0 = __half2float(mt[t * 17 + jj]);
        float b1 = __half2float(mt[i1r * 17 + jj]);
        // scores bounded (|qk|<~1, |mask|<~6) -> exp safe w/o max-subtract
        float p0 = __expf(sv0 + b0);
        float p1 = __expf(sv1 + b1);
        l0 += p0; l1 += p1;
        const float4* vj = (const float4*)(vv + 16 * j);
        float4 v0 = vj[0], v1 = vj[1], v2 = vj[2], v3 = vj[3];
        a00.x = fmaf(p0, v0.x, a00.x); a10.x = fmaf(p1, v0.x, a10.x);
        a00.y = fmaf(p0, v0.y, a00.y); a10.y = fmaf(p1, v0.y, a10.y);
        a00.z = fmaf(p0, v0.z, a00.z); a10.z = fmaf(p1, v0.z, a10.z);
        a00.w = fmaf(p0, v0.w, a00.w); a10.w = fmaf(p1, v0.w, a10.w);
        a01.x = fmaf(p0, v1.x, a01.x); a11.x = fmaf(p1, v1.x, a11.x);
        a01.y = fmaf(p0, v1.y, a01.y); a11.y = fmaf(p1, v1.y, a11.y);
        a01.z = fmaf(p0, v1.z, a01.z); a11.z = fmaf(p1, v1.z, a11.z);
        a01.w = fmaf(p0, v1.w, a01.w); a11.w = fmaf(p1, v1.w, a11.w);
        a02.x = fmaf(p0, v2.x, a02.x); a12.x = fmaf(p1, v2.x, a12.x);
        a02.y = fmaf(p0, v2.y, a02.y); a12.y = fmaf(p1, v2.y, a12.y);
        a02.z = fmaf(p0, v2.z, a02.z); a12.z = fmaf(p1, v2.z, a12.z);
        a02.w = fmaf(p0, v2.w, a02.w); a12.w = fmaf(p1, v2.w, a12.w);
        a03.x = fmaf(p0, v3.x, a03.x); a13.x = fmaf(p1, v3.x, a13.x);
        a03.y = fmaf(p0, v3.y, a03.y); a13.y = fmaf(p1, v3.y, a13.y);
        a03.z = fmaf(p0, v3.z, a03.z); a13.z = fmaf(p1, v3.z, a13.z);
        a03.w = fmaf(p0, v3.w, a03.w); a13.w = fmaf(p1, v3.w, a13.w);
      }
    }
    __syncthreads();
  }

  // epilogue per token
  for (int half = 0; half < 2; half++) {
    bool act = half ? act1 : act0;
    if (!act) continue;
    int i = half ? i1 : t;
    int src = half ? src1 : src0;
    float inv = 1.f / (half ? l1 : l0);
    float o[16];
    if (half) {
      o[0]=a10.x;o[1]=a10.y;o[2]=a10.z;o[3]=a10.w;o[4]=a11.x;o[5]=a11.y;o[6]=a11.z;o[7]=a11.w;
      o[8]=a12.x;o[9]=a12.y;o[10]=a12.z;o[11]=a12.w;o[12]=a13.x;o[13]=a13.y;o[14]=a13.z;o[15]=a13.w;
    } else {
      o[0]=a00.x;o[1]=a00.y;o[2]=a00.z;o[3]=a00.w;o[4]=a01.x;o[5]=a01.y;o[6]=a01.z;o[7]=a01.w;
      o[8]=a02.x;o[9]=a02.y;o[10]=a02.z;o[11]=a02.w;o[12]=a03.x;o[13]=a03.y;o[14]=a03.z;o[15]=a03.w;
    }
    if (use_o) {
      float* dst = obuf + (((s * 125 + w) * NTOK) + i) * 96 + h * 16;
#pragma unroll
      for (int r4 = 0; r4 < 4; r4++) {
        float4 ov = {o[4*r4]*inv, o[4*r4+1]*inv, o[4*r4+2]*inv, o[4*r4+3]*inv};
        ((float4*)dst)[r4] = ov;
      }
    } else {
      const float* Pw = (s ? pwb : pwa) + (16 * h) * 96;
      float ctr[48];
#pragma unroll
      for (int c = 0; c < 48; c++) ctr[c] = 0.f;
#pragma unroll
      for (int d = 0; d < 16; d++) {
        float od = o[d] * inv;
        const float* prow = Pw + d * 96;
#pragma unroll
        for (int c = 0; c < 48; c++) ctr[c] = fmaf(od, prow[c], ctr[c]);
      }
      float* dst = out + s * X1SZ + src * 48;
#pragma unroll
      for (int c = 0; c < 48; c++) atomicAdd(dst + c, ctr[c]);
    }
  }
}

// K1b (O-path): proj + inverse shuffle scatter + residual -> d_out (r1-verified)
__global__ __launch_bounds__(384) void k_proj(
    const float* __restrict__ O,
    const float* __restrict__ xa0, const float* __restrict__ xb0,
    const float* __restrict__ pwa, const float* __restrict__ pba,
    const float* __restrict__ pwb, const float* __restrict__ pbb,
    float* __restrict__ out) {
  int sw = blockIdx.x; int s = sw / 125, w = sw - s * 125;
  int i = threadIdx.x;
  if (i >= NTOK) return;
  const float* Wt = s ? pwb : pwa;
  const float* Bi = s ? pbb : pba;
  const float* orow = O + ((s * 125 + w) * NTOK + i) * 96;
  float acc[48];
#pragma unroll
  for (int c = 0; c < 48; c++) acc[c] = 0.f;
  for (int k = 0; k < 96; k++) {
    float x = orow[k];
#pragma unroll
    for (int c = 0; c < 48; c++) acc[c] = fmaf(x, Wt[k * 96 + c], acc[c]);
  }
  int par; int src = src_index(w, i, par);
  const float* x0 = (s ? xb0 : xa0) + src * 48;
  float* dst = out + s * X1SZ + src * 48;
#pragma unroll
  for (int q = 0; q < 12; q++) {
    float4 xv = ((const float4*)x0)[q];
    float4 o;
    o.x = xv.x + acc[4 * q + 0] + Bi[4 * q + 0];
    o.y = xv.y + acc[4 * q + 1] + Bi[4 * q + 1];
    o.z = xv.z + acc[4 * q + 2] + Bi[4 * q + 2];
    o.w = xv.w + acc[4 * q + 3] + Bi[4 * q + 3];
    ((float4*)dst)[q] = o;
  }
}

// K2: in-place fused LN2 + fc1 + gelu + fc2 + residual; gate channel sums
__global__ __launch_bounds__(256) void k_mlp(
    const float* __restrict__ g2a, const float* __restrict__ b2a,
    const float* __restrict__ g2b, const float* __restrict__ b2b,
    const float* __restrict__ fb1a, const float* __restrict__ w2a,
    const float* __restrict__ fb2a,
    const float* __restrict__ fb1b, const float* __restrict__ w2b,
    const float* __restrict__ fb2b,
    float* __restrict__ out, float* __restrict__ ws) {
  int s = blockIdx.z;
  int t = blockIdx.x * 256 + threadIdx.x;
  __shared__ float red[48];
  if (threadIdx.x < 48) red[threadIdx.x] = 0.f;
  __syncthreads();
  bool act = (t < LQ);
  if (act) {
    float* row = out + s * X1SZ + t * 48;
    float xr[48]; float sm = 0.f, sq = 0.f;
#pragma unroll
    for (int q4 = 0; q4 < 12; q4++) {
      float4 v = ((const float4*)row)[q4];
      xr[4 * q4] = v.x; xr[4 * q4 + 1] = v.y; xr[4 * q4 + 2] = v.z; xr[4 * q4 + 3] = v.w;
      sm += v.x + v.y + v.z + v.w;
      sq += v.x * v.x + v.y * v.y + v.z * v.z + v.w * v.w;
    }
    float m = sm * (1.f / 48.f);
    float r = rsqrtf(sq * (1.f / 48.f) - m * m + 1e-5f);
    const float* G = s ? g2b : g2a;
    const float* B = s ? b2b : b2a;
    const float* W1T = ws + OFF_W1T + s * 18432;
    const float* B1 = s ? fb1b : fb1a;
    const float* W2 = s ? w2b : w2a;
    const float* B2 = s ? fb2b : fb2a;
    float xn[48];
#pragma unroll
    for (int k = 0; k < 48; k++) xn[k] = (xr[k] - m) * r * G[k] + B[k];
    float acc[48];
#pragma unroll
    for (int c = 0; c < 48; c++) acc[c] = B2[c];
    for (int j = 0; j < 384; j++) {
      float hv = B1[j];
      const float* w1r = W1T + j * 48;
#pragma unroll
      for (int k = 0; k < 48; k++) hv = fmaf(xn[k], w1r[k], hv);
      hv = 0.5f * hv * (1.f + erff(hv * 0.70710678118654752f));
      const float* w2r = W2 + j * 48;
#pragma unroll
      for (int c = 0; c < 48; c++) acc[c] = fmaf(hv, w2r[c], acc[c]);
    }
    float fin[48];
#pragma unroll
    for (int c = 0; c < 48; c++) fin[c] = xr[c] + acc[c];
#pragma unroll
    for (int q4 = 0; q4 < 12; q4++) {
      float4 o = {fin[4 * q4], fin[4 * q4 + 1], fin[4 * q4 + 2], fin[4 * q4 + 3]};
      ((float4*)row)[q4] = o;
    }
    if (s == 0) {
#pragma unroll
      for (int c = 0; c < 48; c++) atomicAdd(&red[c], fin[c]);
    }
  }
  __syncthreads();
  if (s == 0 && threadIdx.x < 48) atomicAdd(ws + OFF_MEAN + threadIdx.x, red[threadIdx.x]);
}

// K3: gate scalar
__global__ __launch_bounds__(64) void k_gate(
    const float* __restrict__ ws_mean, const float* __restrict__ gw1,
    const float* __restrict__ gw2, const float* __restrict__ gb2,
    float* __restrict__ g) {
  int j = threadIdx.x;
  float t = 0.f;
  if (j < 12) {
    for (int c = 0; c < 48; c++)
      t = fmaf(ws_mean[c] * (1.f / (float)LQ), gw1[c * 12 + j], t);
    t = fmaxf(t, 0.f) * gw2[j];
  }
  for (int off = 32; off > 0; off >>= 1) t += __shfl_down(t, off);
  if (j == 0) *g = 1.f / (1.f + __expf(-(t + gb2[0])));
}

// K4: out_a += g * out_b
__global__ __launch_bounds__(256) void k_gadd(float* __restrict__ out,
                                              const float* __restrict__ g) {
  int i = blockIdx.x * 256 + threadIdx.x;
  if (i >= X1SZ / 4) return;
  float gv = *g;
  float4* a = (float4*)out;
  const float4* b = (const float4*)(out + X1SZ);
  float4 x = a[i], y = b[i];
  x.x = fmaf(gv, y.x, x.x);
  x.y = fmaf(gv, y.y, x.y);
  x.z = fmaf(gv, y.z, x.z);
  x.w = fmaf(gv, y.w, x.w);
  a[i] = x;
}

extern "C" void kernel_launch(void* const* d_in, const int* in_sizes, int n_in,
                              void* d_out, int out_size, void* d_ws, size_t ws_size,
                              hipStream_t stream) {
  const float* xa    = (const float*)d_in[0];
  const float* xb    = (const float*)d_in[1];
  const float* mask  = (const float*)d_in[2];
  const float* n1ag  = (const float*)d_in[3];
  const float* n1ab  = (const float*)d_in[4];
  const float* n1bg  = (const float*)d_in[5];
  const float* n1bb  = (const float*)d_in[6];
  const float* rpba  = (const float*)d_in[7];
  const float* qkvwa = (const float*)d_in[8];
  const float* qkvba = (const float*)d_in[9];
  const float* pwa   = (const float*)d_in[10];
  const float* pba   = (const float*)d_in[11];
  const float* rpbb  = (const float*)d_in[12];
  const float* qkvwb = (const float*)d_in[13];
  const float* qkvbb = (const float*)d_in[14];
  const float* pwb   = (const float*)d_in[15];
  const float* pbb   = (const float*)d_in[16];
  const float* n2ag  = (const float*)d_in[17];
  const float* n2ab  = (const float*)d_in[18];
  const float* n2bg  = (const float*)d_in[19];
  const float* n2bb  = (const float*)d_in[20];
  const float* w1a   = (const float*)d_in[21];
  const float* fb1a  = (const float*)d_in[22];
  const float* w2a   = (const float*)d_in[23];
  const float* fb2a  = (const float*)d_in[24];
  const float* w1b   = (const float*)d_in[25];
  const float* fb1b  = (const float*)d_in[26];
  const float* w2b   = (const float*)d_in[27];
  const float* fb2b  = (const float*)d_in[28];
  const float* gw1   = (const float*)d_in[29];
  const float* gw2   = (const float*)d_in[30];
  const float* gb2   = (const float*)d_in[31];
  float* ws  = (float*)d_ws;
  float* out = (float*)d_out;

  int use_o = (ws_size >= O_BYTES_NEEDED) ? 1 : 0;  // constant per session

  hipLaunchKernelGGL(k_init, dim3(use_o ? 1 : 4020), dim3(256), 0, stream,
                     xa, xb, pba, pbb, out, ws, use_o ? 0 : 1);
  hipLaunchKernelGGL(k_tr, dim3(144), dim3(256), 0, stream, w1a, w1b, ws);
  hipLaunchKernelGGL(k_attn, dim3(1536), dim3(192), 0, stream,
                     xa, xb, n1ag, n1ab, n1bg, n1bb,
                     qkvwa, qkvba, qkvwb, qkvbb, pwa, pwb,
                     rpba, rpbb, mask, out, ws + OFF_O, use_o);
  if (use_o) {
    hipLaunchKernelGGL(k_proj, dim3(250), dim3(384), 0, stream,
                       ws + OFF_O, xa, xb, pwa, pba, pwb, pbb, out);
  }
  hipLaunchKernelGGL(k_mlp, dim3(168, 1, 2), dim3(256), 0, stream,
                     n2ag, n2ab, n2bg, n2bb,
                     fb1a, w2a, fb2a, fb1b, w2b, fb2b, out, ws);
  hipLaunchKernelGGL(k_gate, dim3(1), dim3(64), 0, stream,
                     ws + OFF_MEAN, gw1, gw2, gb2, ws + OFF_MEAN + 48);
  hipLaunchKernelGGL(k_gadd, dim3(2011), dim3(256), 0, stream,
                     out, ws + OFF_MEAN + 48);
}

// Round 4
// 1525.889 us; speedup vs baseline: 1.9136x; 1.9136x over previous
//
#include <hip/hip_runtime.h>

#define LQ    42875      // 35^3 tokens
#define NTOK  343
#define X1SZ  2058000    // LQ*48

// ws float offsets. Base usage ~150 KB; O-path adds 33 MB (gated on ws_size).
#define OFF_MEAN 0       // 48 channel sums + 1 gate scalar
#define OFF_W1T  64      // w1^T: [s][384][48], 2*18432 floats
#define OFF_O    36928   // O[s][w][i][96]: 8,232,000 floats (only if ws_size>=34MB)
#define O_BYTES_NEEDED 34000000ull

__device__ __forceinline__ int src_index(int w, int i, int& par) {
  int gi = w / 25, gj = (w / 5) % 5, gk = w % 5;
  int ph = i / 49, pw = (i / 7) % 7, pt = i % 7;
  int hs = gi * 7 + ph + 3; if (hs >= 35) hs -= 35;
  int wd = gj * 7 + pw + 3; if (wd >= 35) wd -= 35;
  int td = gk * 7 + pt + 3; if (td >= 35) td -= 35;
  par = ((hs / 7) + (wd / 7) + (td / 7)) & 1;
  return (hs * 35 + wd) * 35 + td;
}

// K0: zero gate meanbuf; optionally prefill d_out = x0 + proj_bias (atomic path)
__global__ __launch_bounds__(256) void k_init(
    const float* __restrict__ xa, const float* __restrict__ xb,
    const float* __restrict__ pba, const float* __restrict__ pbb,
    float* __restrict__ out, float* __restrict__ ws, int prefill) {
  if (blockIdx.x == 0 && threadIdx.x < 49) ws[threadIdx.x] = 0.f;
  if (!prefill) return;
  int idx4 = blockIdx.x * 256 + threadIdx.x;
  if (idx4 >= 2 * (X1SZ / 4)) return;
  int s = (idx4 >= (X1SZ / 4)) ? 1 : 0;
  int j4 = idx4 - s * (X1SZ / 4);
  int c0 = (j4 * 4) % 48;
  float4 xv = ((const float4*)(s ? xb : xa))[j4];
  const float* pb = (s ? pbb : pba) + c0;
  float4 o;
  o.x = xv.x + pb[0]; o.y = xv.y + pb[1]; o.z = xv.z + pb[2]; o.w = xv.w + pb[3];
  ((float4*)out)[idx4] = o;
}

// K0b: transpose fc1 weights (48,384)->(384,48) for contiguous k_mlp rows
__global__ __launch_bounds__(256) void k_tr(
    const float* __restrict__ w1a, const float* __restrict__ w1b,
    float* __restrict__ ws) {
  int idx = blockIdx.x * 256 + threadIdx.x;
  if (idx >= 2 * 18432) return;
  int s = (idx >= 18432) ? 1 : 0;
  int e = idx - s * 18432;
  int j = e / 48, k = e - j * 48;
  ws[OFF_W1T + s * 18432 + j * 48 + k] = (s ? w1b : w1a)[k * 384 + j];
}

// per-token fused LN1 + shuffle-gather + QKV for one head; verified rounds 2-3
__device__ __forceinline__ int qkv_one(
    int w, int i, int s,
    const float* __restrict__ xa, const float* __restrict__ xb,
    const float* __restrict__ ga, const float* __restrict__ ba,
    const float* __restrict__ gb, const float* __restrict__ bb,
    const float* __restrict__ qw, const float* __restrict__ qb, int h,
    float* __restrict__ qout, float* kk, float* vv) {
  int par; int src = src_index(w, i, par);
  const float* xo = (s ? xb : xa) + src * 48;
  const float* xt = (s ? xa : xb) + src * 48;
  const float* go = s ? gb : ga; const float* bo = s ? bb : ba;
  const float* gt = s ? ga : gb; const float* bt = s ? ba : bb;
  float own[48], up[48];
  {
    float v[48]; float sm = 0.f, sq = 0.f;
#pragma unroll
    for (int q4 = 0; q4 < 12; q4++) {
      float4 tv = ((const float4*)xo)[q4];
      v[4 * q4] = tv.x; v[4 * q4 + 1] = tv.y; v[4 * q4 + 2] = tv.z; v[4 * q4 + 3] = tv.w;
      sm += tv.x + tv.y + tv.z + tv.w;
      sq += tv.x * tv.x + tv.y * tv.y + tv.z * tv.z + tv.w * tv.w;
    }
    float m = sm * (1.f / 48.f);
    float r = rsqrtf(sq * (1.f / 48.f) - m * m + 1e-5f);
#pragma unroll
    for (int k = 0; k < 48; k++) own[k] = (v[k] - m) * r * go[k] + bo[k];
  }
  {
    float v[48]; float sm = 0.f, sq = 0.f;
#pragma unroll
    for (int q4 = 0; q4 < 12; q4++) {
      float4 tv = ((const float4*)xt)[q4];
      v[4 * q4] = tv.x; v[4 * q4 + 1] = tv.y; v[4 * q4 + 2] = tv.z; v[4 * q4 + 3] = tv.w;
      sm += tv.x + tv.y + tv.z + tv.w;
      sq += tv.x * tv.x + tv.y * tv.y + tv.z * tv.z + tv.w * tv.w;
    }
    float m = sm * (1.f / 48.f);
    float r = rsqrtf(sq * (1.f / 48.f) - m * m + 1e-5f);
#pragma unroll
    for (int k = 0; k < 48; k++)
      up[k] = par ? own[k] : ((v[k] - m) * r * gt[k] + bt[k]);
  }
  const float* Wt = qw + 16 * h;
  const float* Bq = qb + 16 * h;
  float kr[16], vr[16];
#pragma unroll
  for (int d = 0; d < 16; d++) { qout[d] = 0.f; kr[d] = 0.f; vr[d] = 0.f; }
#pragma unroll
  for (int kx = 0; kx < 96; kx++) {
    float xv = (kx < 48) ? own[kx] : up[kx - 48];
    const float* row = Wt + kx * 288;
#pragma unroll
    for (int d = 0; d < 16; d++) {
      qout[d] = fmaf(xv, row[d], qout[d]);
      kr[d] = fmaf(xv, row[96 + d], kr[d]);
      vr[d] = fmaf(xv, row[192 + d], vr[d]);
    }
  }
#pragma unroll
  for (int d = 0; d < 16; d++) {
    qout[d] = (qout[d] + Bq[d]) * 0.25f;
    kr[d] += Bq[96 + d];
    vr[d] += Bq[192 + d];
  }
  float* kd = kk + i * 16; float* vd = vv + i * 16;
#pragma unroll
  for (int r4 = 0; r4 < 4; r4++) {
    float4 kvv = {kr[4 * r4], kr[4 * r4 + 1], kr[4 * r4 + 2], kr[4 * r4 + 3]};
    float4 vvv = {vr[4 * r4], vr[4 * r4 + 1], vr[4 * r4 + 2], vr[4 * r4 + 3]};
    ((float4*)kd)[r4] = kvv;
    ((float4*)vd)[r4] = vvv;
  }
  return src;
}

// K1: fused attention, block=(w,s,h) XCD-swizzled, 192 thr, 2 tokens/thread.
// j-loop batches 4 keys per iter: 4 independent QK chains + 16 PV chains (ILP),
// single barrier, bias read directly (mask via L1/L2, rpb via LDS).
__global__ __launch_bounds__(192) void k_attn(
    const float* __restrict__ xa, const float* __restrict__ xb,
    const float* __restrict__ ga, const float* __restrict__ ba,
    const float* __restrict__ gb, const float* __restrict__ bb,
    const float* __restrict__ qwa, const float* __restrict__ qba,
    const float* __restrict__ qwb, const float* __restrict__ qbb,
    const float* __restrict__ pwa, const float* __restrict__ pwb,
    const float* __restrict__ rpa, const float* __restrict__ rpbp,
    const float* __restrict__ mask,
    float* __restrict__ out, float* __restrict__ obuf, int use_o) {
  int bid = blockIdx.x;
  int xcd = bid & 7, q8 = bid >> 3;
  int u = q8 / 12, inst = q8 - u * 12;
  int w = u * 8 + xcd;
  if (w >= 125) return;
  int s = inst & 1, h = inst >> 1;

  __shared__ float kk[NTOK * 16];     // 21952 B
  __shared__ float vv[NTOK * 16];     // 21952 B
  __shared__ float rpbl[2197];        //  8788 B   -> 52.7 KB, 3 blocks/CU

  const float* rp = s ? rpbp : rpa;
  for (int idx = threadIdx.x; idx < 2197; idx += 192) rpbl[idx] = rp[idx * 6 + h];

  int t = threadIdx.x;
  bool act0 = (t < 172);
  bool act1 = (t < 171);
  int i1 = t + 172;              // token 2 (rows 172..342)
  int i1c = act1 ? i1 : 0;

  const float* qw = s ? qwb : qwa;
  const float* qb = s ? qbb : qba;
  float q0[16], q1[16];
#pragma unroll
  for (int d = 0; d < 16; d++) { q0[d] = 0.f; q1[d] = 0.f; }
  int src0 = 0, src1 = 0;
  if (act0) src0 = qkv_one(w, t, s, xa, xb, ga, ba, gb, bb, qw, qb, h, q0, kk, vv);
  if (act1) src1 = qkv_one(w, i1, s, xa, xb, ga, ba, gb, bb, qw, qb, h, q1, kk, vv);
  __syncthreads();

  // all lanes t<192<343 have valid row indices; inactive lanes compute garbage
  // safely and skip the epilogue.
  int basei0 = (t / 49) * 169 + ((t / 7) % 7) * 13 + (t % 7) + 1098;
  int basei1 = (i1c / 49) * 169 + ((i1c / 7) % 7) * 13 + (i1c % 7) + 1098;
  const float* mrow0 = mask + (w * NTOK + t) * NTOK;
  const float* mrow1 = mask + (w * NTOK + i1c) * NTOK;

  float4 qa[4], qbv[4];
#pragma unroll
  for (int c = 0; c < 4; c++) {
    qa[c] = make_float4(q0[4 * c], q0[4 * c + 1], q0[4 * c + 2], q0[4 * c + 3]);
    qbv[c] = make_float4(q1[4 * c], q1[4 * c + 1], q1[4 * c + 2], q1[4 * c + 3]);
  }
  const float4* kb = (const float4*)kk;
  const float4* vb = (const float4*)vv;
  float4 acc0[4], acc1[4];
#pragma unroll
  for (int c = 0; c < 4; c++) {
    acc0[c] = make_float4(0.f, 0.f, 0.f, 0.f);
    acc1[c] = make_float4(0.f, 0.f, 0.f, 0.f);
  }
  float l0 = 0.f, l1 = 0.f;

  for (int j0 = 0; j0 < 340; j0 += 4) {
    // issue bias loads first (latency overlaps the FMA block below)
    float m00 = mrow0[j0], m01 = mrow0[j0 + 1], m02 = mrow0[j0 + 2], m03 = mrow0[j0 + 3];
    float m10 = mrow1[j0], m11 = mrow1[j0 + 1], m12 = mrow1[j0 + 2], m13 = mrow1[j0 + 3];
    int bj0 = (j0 / 49) * 169 + ((j0 / 7) % 7) * 13 + (j0 % 7);
    int j1_ = j0 + 1, j2_ = j0 + 2, j3_ = j0 + 3;
    int bj1 = (j1_ / 49) * 169 + ((j1_ / 7) % 7) * 13 + (j1_ % 7);
    int bj2 = (j2_ / 49) * 169 + ((j2_ / 7) % 7) * 13 + (j2_ % 7);
    int bj3 = (j3_ / 49) * 169 + ((j3_ / 7) % 7) * 13 + (j3_ % 7);
    float r00 = rpbl[basei0 - bj0], r01 = rpbl[basei0 - bj1];
    float r02 = rpbl[basei0 - bj2], r03 = rpbl[basei0 - bj3];
    float r10 = rpbl[basei1 - bj0], r11 = rpbl[basei1 - bj1];
    float r12 = rpbl[basei1 - bj2], r13 = rpbl[basei1 - bj3];

    float sA0 = 0.f, sA1 = 0.f, sA2 = 0.f, sA3 = 0.f;
    float sB0 = 0.f, sB1 = 0.f, sB2 = 0.f, sB3 = 0.f;
#pragma unroll
    for (int c = 0; c < 4; c++) {
      float4 k0 = kb[(j0 + 0) * 4 + c];
      float4 k1 = kb[(j0 + 1) * 4 + c];
      float4 k2 = kb[(j0 + 2) * 4 + c];
      float4 k3 = kb[(j0 + 3) * 4 + c];
      float4 a = qa[c], b = qbv[c];
      sA0 = fmaf(a.x, k0.x, sA0); sA0 = fmaf(a.y, k0.y, sA0);
      sA0 = fmaf(a.z, k0.z, sA0); sA0 = fmaf(a.w, k0.w, sA0);
      sA1 = fmaf(a.x, k1.x, sA1); sA1 = fmaf(a.y, k1.y, sA1);
      sA1 = fmaf(a.z, k1.z, sA1); sA1 = fmaf(a.w, k1.w, sA1);
      sA2 = fmaf(a.x, k2.x, sA2); sA2 = fmaf(a.y, k2.y, sA2);
      sA2 = fmaf(a.z, k2.z, sA2); sA2 = fmaf(a.w, k2.w, sA2);
      sA3 = fmaf(a.x, k3.x, sA3); sA3 = fmaf(a.y, k3.y, sA3);
      sA3 = fmaf(a.z, k3.z, sA3); sA3 = fmaf(a.w, k3.w, sA3);
      sB0 = fmaf(b.x, k0.x, sB0); sB0 = fmaf(b.y, k0.y, sB0);
      sB0 = fmaf(b.z, k0.z, sB0); sB0 = fmaf(b.w, k0.w, sB0);
      sB1 = fmaf(b.x, k1.x, sB1); sB1 = fmaf(b.y, k1.y, sB1);
      sB1 = fmaf(b.z, k1.z, sB1); sB1 = fmaf(b.w, k1.w, sB1);
      sB2 = fmaf(b.x, k2.x, sB2); sB2 = fmaf(b.y, k2.y, sB2);
      sB2 = fmaf(b.z, k2.z, sB2); sB2 = fmaf(b.w, k2.w, sB2);
      sB3 = fmaf(b.x, k3.x, sB3); sB3 = fmaf(b.y, k3.y, sB3);
      sB3 = fmaf(b.z, k3.z, sB3); sB3 = fmaf(b.w, k3.w, sB3);
    }
    // scores bounded (|qk|<~1, |mask|<~6) -> exp safe without max-subtract
    float pA0 = __expf(sA0 + m00 + r00);
    float pA1 = __expf(sA1 + m01 + r01);
    float pA2 = __expf(sA2 + m02 + r02);
    float pA3 = __expf(sA3 + m03 + r03);
    float pB0 = __expf(sB0 + m10 + r10);
    float pB1 = __expf(sB1 + m11 + r11);
    float pB2 = __expf(sB2 + m12 + r12);
    float pB3 = __expf(sB3 + m13 + r13);
    l0 += (pA0 + pA1) + (pA2 + pA3);
    l1 += (pB0 + pB1) + (pB2 + pB3);
#pragma unroll
    for (int c = 0; c < 4; c++) {
      float4 v0 = vb[(j0 + 0) * 4 + c];
      float4 v1 = vb[(j0 + 1) * 4 + c];
      float4 v2 = vb[(j0 + 2) * 4 + c];
      float4 v3 = vb[(j0 + 3) * 4 + c];
      acc0[c].x = fmaf(pA0, v0.x, acc0[c].x); acc0[c].x = fmaf(pA1, v1.x, acc0[c].x);
      acc0[c].x = fmaf(pA2, v2.x, acc0[c].x); acc0[c].x = fmaf(pA3, v3.x, acc0[c].x);
      acc0[c].y = fmaf(pA0, v0.y, acc0[c].y); acc0[c].y = fmaf(pA1, v1.y, acc0[c].y);
      acc0[c].y = fmaf(pA2, v2.y, acc0[c].y); acc0[c].y = fmaf(pA3, v3.y, acc0[c].y);
      acc0[c].z = fmaf(pA0, v0.z, acc0[c].z); acc0[c].z = fmaf(pA1, v1.z, acc0[c].z);
      acc0[c].z = fmaf(pA2, v2.z, acc0[c].z); acc0[c].z = fmaf(pA3, v3.z, acc0[c].z);
      acc0[c].w = fmaf(pA0, v0.w, acc0[c].w); acc0[c].w = fmaf(pA1, v1.w, acc0[c].w);
      acc0[c].w = fmaf(pA2, v2.w, acc0[c].w); acc0[c].w = fmaf(pA3, v3.w, acc0[c].w);
      acc1[c].x = fmaf(pB0, v0.x, acc1[c].x); acc1[c].x = fmaf(pB1, v1.x, acc1[c].x);
      acc1[c].x = fmaf(pB2, v2.x, acc1[c].x); acc1[c].x = fmaf(pB3, v3.x, acc1[c].x);
      acc1[c].y = fmaf(pB0, v0.y, acc1[c].y); acc1[c].y = fmaf(pB1, v1.y, acc1[c].y);
      acc1[c].y = fmaf(pB2, v2.y, acc1[c].y); acc1[c].y = fmaf(pB3, v3.y, acc1[c].y);
      acc1[c].z = fmaf(pB0, v0.z, acc1[c].z); acc1[c].z = fmaf(pB1, v1.z, acc1[c].z);
      acc1[c].z = fmaf(pB2, v2.z, acc1[c].z); acc1[c].z = fmaf(pB3, v3.z, acc1[c].z);
      acc1[c].w = fmaf(pB0, v0.w, acc1[c].w); acc1[c].w = fmaf(pB1, v1.w, acc1[c].w);
      acc1[c].w = fmaf(pB2, v2.w, acc1[c].w); acc1[c].w = fmaf(pB3, v3.w, acc1[c].w);
    }
  }
  // tail j = 340..342
  for (int j = 340; j < NTOK; j++) {
    int bj = (j / 49) * 169 + ((j / 7) % 7) * 13 + (j % 7);
    float m0 = mrow0[j], m1 = mrow1[j];
    float r0 = rpbl[basei0 - bj], r1 = rpbl[basei1 - bj];
    float sA = 0.f, sB = 0.f;
#pragma unroll
    for (int c = 0; c < 4; c++) {
      float4 kv = kb[j * 4 + c];
      float4 a = qa[c], b = qbv[c];
      sA = fmaf(a.x, kv.x, sA); sA = fmaf(a.y, kv.y, sA);
      sA = fmaf(a.z, kv.z, sA); sA = fmaf(a.w, kv.w, sA);
      sB = fmaf(b.x, kv.x, sB); sB = fmaf(b.y, kv.y, sB);
      sB = fmaf(b.z, kv.z, sB); sB = fmaf(b.w, kv.w, sB);
    }
    float pA = __expf(sA + m0 + r0);
    float pB = __expf(sB + m1 + r1);
    l0 += pA; l1 += pB;
#pragma unroll
    for (int c = 0; c < 4; c++) {
      float4 vv4 = vb[j * 4 + c];
      acc0[c].x = fmaf(pA, vv4.x, acc0[c].x); acc0[c].y = fmaf(pA, vv4.y, acc0[c].y);
      acc0[c].z = fmaf(pA, vv4.z, acc0[c].z); acc0[c].w = fmaf(pA, vv4.w, acc0[c].w);
      acc1[c].x = fmaf(pB, vv4.x, acc1[c].x); acc1[c].y = fmaf(pB, vv4.y, acc1[c].y);
      acc1[c].z = fmaf(pB, vv4.z, acc1[c].z); acc1[c].w = fmaf(pB, vv4.w, acc1[c].w);
    }
  }

  // epilogue per token
  for (int half = 0; half < 2; half++) {
    bool act = half ? act1 : act0;
    if (!act) continue;
    int i = half ? i1 : t;
    int src = half ? src1 : src0;
    float inv = 1.f / (half ? l1 : l0);
    float o[16];
#pragma unroll
    for (int c = 0; c < 4; c++) {
      float4 a = half ? acc1[c] : acc0[c];
      o[4 * c] = a.x; o[4 * c + 1] = a.y; o[4 * c + 2] = a.z; o[4 * c + 3] = a.w;
    }
    if (use_o) {
      float* dst = obuf + (((s * 125 + w) * NTOK) + i) * 96 + h * 16;
#pragma unroll
      for (int r4 = 0; r4 < 4; r4++) {
        float4 ov = {o[4*r4]*inv, o[4*r4+1]*inv, o[4*r4+2]*inv, o[4*r4+3]*inv};
        ((float4*)dst)[r4] = ov;
      }
    } else {
      const float* Pw = (s ? pwb : pwa) + (16 * h) * 96;
      float ctr[48];
#pragma unroll
      for (int c = 0; c < 48; c++) ctr[c] = 0.f;
#pragma unroll
      for (int d = 0; d < 16; d++) {
        float od = o[d] * inv;
        const float* prow = Pw + d * 96;
#pragma unroll
        for (int c = 0; c < 48; c++) ctr[c] = fmaf(od, prow[c], ctr[c]);
      }
      float* dst = out + s * X1SZ + src * 48;
#pragma unroll
      for (int c = 0; c < 48; c++) atomicAdd(dst + c, ctr[c]);
    }
  }
}

// K1b (O-path): proj + inverse shuffle scatter + residual -> d_out
__global__ __launch_bounds__(384) void k_proj(
    const float* __restrict__ O,
    const float* __restrict__ xa0, const float* __restrict__ xb0,
    const float* __restrict__ pwa, const float* __restrict__ pba,
    const float* __restrict__ pwb, const float* __restrict__ pbb,
    float* __restrict__ out) {
  int sw = blockIdx.x; int s = sw / 125, w = sw - s * 125;
  int i = threadIdx.x;
  if (i >= NTOK) return;
  const float* Wt = s ? pwb : pwa;
  const float* Bi = s ? pbb : pba;
  const float* orow = O + ((s * 125 + w) * NTOK + i) * 96;
  float acc[48];
#pragma unroll
  for (int c = 0; c < 48; c++) acc[c] = 0.f;
  for (int k = 0; k < 96; k++) {
    float x = orow[k];
#pragma unroll
    for (int c = 0; c < 48; c++) acc[c] = fmaf(x, Wt[k * 96 + c], acc[c]);
  }
  int par; int src = src_index(w, i, par);
  const float* x0 = (s ? xb0 : xa0) + src * 48;
  float* dst = out + s * X1SZ + src * 48;
#pragma unroll
  for (int q = 0; q < 12; q++) {
    float4 xv = ((const float4*)x0)[q];
    float4 o;
    o.x = xv.x + acc[4 * q + 0] + Bi[4 * q + 0];
    o.y = xv.y + acc[4 * q + 1] + Bi[4 * q + 1];
    o.z = xv.z + acc[4 * q + 2] + Bi[4 * q + 2];
    o.w = xv.w + acc[4 * q + 3] + Bi[4 * q + 3];
    ((float4*)dst)[q] = o;
  }
}

// K2: in-place fused LN2 + fc1 + gelu + fc2 + residual; gate channel sums
__global__ __launch_bounds__(256) void k_mlp(
    const float* __restrict__ g2a, const float* __restrict__ b2a,
    const float* __restrict__ g2b, const float* __restrict__ b2b,
    const float* __restrict__ fb1a, const float* __restrict__ w2a,
    const float* __restrict__ fb2a,
    const float* __restrict__ fb1b, const float* __restrict__ w2b,
    const float* __restrict__ fb2b,
    float* __restrict__ out, float* __restrict__ ws) {
  int s = blockIdx.z;
  int t = blockIdx.x * 256 + threadIdx.x;
  __shared__ float red[48];
  if (threadIdx.x < 48) red[threadIdx.x] = 0.f;
  __syncthreads();
  bool act = (t < LQ);
  if (act) {
    float* row = out + s * X1SZ + t * 48;
    float xr[48]; float sm = 0.f, sq = 0.f;
#pragma unroll
    for (int q4 = 0; q4 < 12; q4++) {
      float4 v = ((const float4*)row)[q4];
      xr[4 * q4] = v.x; xr[4 * q4 + 1] = v.y; xr[4 * q4 + 2] = v.z; xr[4 * q4 + 3] = v.w;
      sm += v.x + v.y + v.z + v.w;
      sq += v.x * v.x + v.y * v.y + v.z * v.z + v.w * v.w;
    }
    float m = sm * (1.f / 48.f);
    float r = rsqrtf(sq * (1.f / 48.f) - m * m + 1e-5f);
    const float* G = s ? g2b : g2a;
    const float* B = s ? b2b : b2a;
    const float* W1T = ws + OFF_W1T + s * 18432;
    const float* B1 = s ? fb1b : fb1a;
    const float* W2 = s ? w2b : w2a;
    const float* B2 = s ? fb2b : fb2a;
    float xn[48];
#pragma unroll
    for (int k = 0; k < 48; k++) xn[k] = (xr[k] - m) * r * G[k] + B[k];
    float acc[48];
#pragma unroll
    for (int c = 0; c < 48; c++) acc[c] = B2[c];
    for (int j = 0; j < 384; j++) {
      float hv = B1[j];
      const float* w1r = W1T + j * 48;
#pragma unroll
      for (int k = 0; k < 48; k++) hv = fmaf(xn[k], w1r[k], hv);
      hv = 0.5f * hv * (1.f + erff(hv * 0.70710678118654752f));
      const float* w2r = W2 + j * 48;
#pragma unroll
      for (int c = 0; c < 48; c++) acc[c] = fmaf(hv, w2r[c], acc[c]);
    }
    float fin[48];
#pragma unroll
    for (int c = 0; c < 48; c++) fin[c] = xr[c] + acc[c];
#pragma unroll
    for (int q4 = 0; q4 < 12; q4++) {
      float4 o = {fin[4 * q4], fin[4 * q4 + 1], fin[4 * q4 + 2], fin[4 * q4 + 3]};
      ((float4*)row)[q4] = o;
    }
    if (s == 0) {
#pragma unroll
      for (int c = 0; c < 48; c++) atomicAdd(&red[c], fin[c]);
    }
  }
  __syncthreads();
  if (s == 0 && threadIdx.x < 48) atomicAdd(ws + OFF_MEAN + threadIdx.x, red[threadIdx.x]);
}

// K3: gate scalar
__global__ __launch_bounds__(64) void k_gate(
    const float* __restrict__ ws_mean, const float* __restrict__ gw1,
    const float* __restrict__ gw2, const float* __restrict__ gb2,
    float* __restrict__ g) {
  int j = threadIdx.x;
  float t = 0.f;
  if (j < 12) {
    for (int c = 0; c < 48; c++)
      t = fmaf(ws_mean[c] * (1.f / (float)LQ), gw1[c * 12 + j], t);
    t = fmaxf(t, 0.f) * gw2[j];
  }
  for (int off = 32; off > 0; off >>= 1) t += __shfl_down(t, off);
  if (j == 0) *g = 1.f / (1.f + __expf(-(t + gb2[0])));
}

// K4: out_a += g * out_b
__global__ __launch_bounds__(256) void k_gadd(float* __restrict__ out,
                                              const float* __restrict__ g) {
  int i = blockIdx.x * 256 + threadIdx.x;
  if (i >= X1SZ / 4) return;
  float gv = *g;
  float4* a = (float4*)out;
  const float4* b = (const float4*)(out + X1SZ);
  float4 x = a[i], y = b[i];
  x.x = fmaf(gv, y.x, x.x);
  x.y = fmaf(gv, y.y, x.y);
  x.z = fmaf(gv, y.z, x.z);
  x.w = fmaf(gv, y.w, x.w);
  a[i] = x;
}

extern "C" void kernel_launch(void* const* d_in, const int* in_sizes, int n_in,
                              void* d_out, int out_size, void* d_ws, size_t ws_size,
                              hipStream_t stream) {
  const float* xa    = (const float*)d_in[0];
  const float* xb    = (const float*)d_in[1];
  const float* mask  = (const float*)d_in[2];
  const float* n1ag  = (const float*)d_in[3];
  const float* n1ab  = (const float*)d_in[4];
  const float* n1bg  = (const float*)d_in[5];
  const float* n1bb  = (const float*)d_in[6];
  const float* rpba  = (const float*)d_in[7];
  const float* qkvwa = (const float*)d_in[8];
  const float* qkvba = (const float*)d_in[9];
  const float* pwa   = (const float*)d_in[10];
  const float* pba   = (const float*)d_in[11];
  const float* rpbb  = (const float*)d_in[12];
  const float* qkvwb = (const float*)d_in[13];
  const float* qkvbb = (const float*)d_in[14];
  const float* pwb   = (const float*)d_in[15];
  const float* pbb   = (const float*)d_in[16];
  const float* n2ag  = (const float*)d_in[17];
  const float* n2ab  = (const float*)d_in[18];
  const float* n2bg  = (const float*)d_in[19];
  const float* n2bb  = (const float*)d_in[20];
  const float* w1a   = (const float*)d_in[21];
  const float* fb1a  = (const float*)d_in[22];
  const float* w2a   = (const float*)d_in[23];
  const float* fb2a  = (const float*)d_in[24];
  const float* w1b   = (const float*)d_in[25];
  const float* fb1b  = (const float*)d_in[26];
  const float* w2b   = (const float*)d_in[27];
  const float* fb2b  = (const float*)d_in[28];
  const float* gw1   = (const float*)d_in[29];
  const float* gw2   = (const float*)d_in[30];
  const float* gb2   = (const float*)d_in[31];
  float* ws  = (float*)d_ws;
  float* out = (float*)d_out;

  int use_o = (ws_size >= O_BYTES_NEEDED) ? 1 : 0;  // constant per session

  hipLaunchKernelGGL(k_init, dim3(use_o ? 1 : 4020), dim3(256), 0, stream,
                     xa, xb, pba, pbb, out, ws, use_o ? 0 : 1);
  hipLaunchKernelGGL(k_tr, dim3(144), dim3(256), 0, stream, w1a, w1b, ws);
  hipLaunchKernelGGL(k_attn, dim3(1536), dim3(192), 0, stream,
                     xa, xb, n1ag, n1ab, n1bg, n1bb,
                     qkvwa, qkvba, qkvwb, qkvbb, pwa, pwb,
                     rpba, rpbb, mask, out, ws + OFF_O, use_o);
  if (use_o) {
    hipLaunchKernelGGL(k_proj, dim3(250), dim3(384), 0, stream,
                       ws + OFF_O, xa, xb, pwa, pba, pwb, pbb, out);
  }
  hipLaunchKernelGGL(k_mlp, dim3(168, 1, 2), dim3(256), 0, stream,
                     n2ag, n2ab, n2bg, n2bb,
                     fb1a, w2a, fb2a, fb1b, w2b, fb2b, out, ws);
  hipLaunchKernelGGL(k_gate, dim3(1), dim3(64), 0, stream,
                     ws + OFF_MEAN, gw1, gw2, gb2, ws + OFF_MEAN + 48);
  hipLaunchKernelGGL(k_gadd, dim3(2011), dim3(256), 0, stream,
                     out, ws + OFF_MEAN + 48);
}